// Round 3
// baseline (261.243 us; speedup 1.0000x reference)
//
#include <hip/hip_runtime.h>

// EfficientCrossAttentionHead: B=4, N=16384, C=256, H=64, fp32 in/out.
//   kW_pack : weights -> bf16 MFMA B-fragment layout in ws
//   kA_proj : x -> (k,q,v) via MFMA; q logits -> ws (bf16, coalesced);
//             partial (sum exp(k)*v, sum exp(k)) per block slot
//   kB_reduce: partials -> w[bs][64][64] = (sum e*v)/Z
//   kC_out  : out = softmax_row(q_s) @ w_{1-s}  (MFMA, bf16 in / f32 acc)
// ws usage ~34.3 MB.

#define B_ 4
#define N_ 16384
#define C_ 256

typedef float f32x4 __attribute__((ext_vector_type(4)));
typedef __bf16 bf16x8 __attribute__((ext_vector_type(8)));
typedef unsigned short us8 __attribute__((ext_vector_type(8)));

__device__ __forceinline__ unsigned short f2bf(float f) {
  union { float f; unsigned u; } v; v.f = f;
  return (unsigned short)((v.u + 0x7FFFu + ((v.u >> 16) & 1u)) >> 16);
}
__device__ __forceinline__ float bf2f(unsigned short h) {
  union { unsigned u; float f; } v; v.u = ((unsigned)h) << 16;
  return v.f;
}

// ws byte offsets
#define WPACK_OFF 0u           // [2][12][8][64][8] bf16 = 196608 B
#define Q_OFF     262144u      // q logits bf16 [8][16384][64] = 16 MB
#define PNW_OFF   17039360u    // partial nw [8][128][4096] f32 = 16 MB
#define PZ_OFF    33816576u    // partial z  [8][128][64]  f32 = 256 KB
#define WFIN_OFF  34078720u    // w final [8][4096] f32 = 128 KB

__global__ __launch_bounds__(256) void kW_pack(
    const float* __restrict__ Wk0, const float* __restrict__ Wk1,
    const float* __restrict__ Wq0, const float* __restrict__ Wq1,
    const float* __restrict__ Wv0, const float* __restrict__ Wv1,
    unsigned short* __restrict__ wpack) {
  int t = blockIdx.x * 256 + threadIdx.x;  // [0, 98304)
  int i = t & 7;
  int lane = (t >> 3) & 63;
  int q = t >> 9;            // [0,192)
  int ks = q & 7;
  int sj = q >> 3;           // [0,24)
  int s = sj / 12;
  int j = sj - s * 12;       // col-frag 0..11 (k:0-3, q:4-7, v:8-11)
  int gc = 16 * j + (lane & 15);
  int c = 32 * ks + ((lane >> 4) << 3) + i;
  int m = gc >> 6, row = gc & 63;
  const float* W;
  if (s == 0) W = (m == 0) ? Wk0 : (m == 1) ? Wq0 : Wv0;
  else        W = (m == 0) ? Wk1 : (m == 1) ? Wq1 : Wv1;
  wpack[t] = f2bf(W[row * 256 + c]);
}

__global__ __launch_bounds__(256, 3) void kA_proj(
    const float* __restrict__ x0, const float* __restrict__ x1,
    const unsigned short* __restrict__ wpack,
    unsigned short* __restrict__ qbuf, float* __restrict__ pnw,
    float* __restrict__ pz) {
  int pb = blockIdx.x;       // 0..127 partial slot
  int bs = blockIdx.y;       // 0..7 : b = bs>>1, s = bs&1
  int b = bs >> 1, s = bs & 1;
  const float* x = (s ? x1 : x0) + (size_t)b * N_ * C_;
  int t = threadIdx.x;
  int w = t >> 6;            // wave 0..3; owns output cols [48w, 48w+48)
  int l = t & 63;
  int l15 = l & 15, lg = l >> 4;

  // 32 KB: x tile [64][256] bf16 swizzled; after phase 1, first 24 KB is
  // overlaid with pT (8K) | vT (8K) | qs (8K).
  __shared__ __align__(16) char xsb[32768];
  char* pTb = xsb;
  char* vTb = xsb + 8192;
  char* qsb = xsb + 16384;

  const char* wbase = (const char*)wpack + (size_t)s * 12 * 8 * 64 * 16;

  f32x4 nwacc[4];
#pragma unroll
  for (int j2 = 0; j2 < 4; ++j2) { f32x4 z = {0.f,0.f,0.f,0.f}; nwacc[j2] = z; }
  float zacc[3] = {0.f, 0.f, 0.f};

  for (int it = 0; it < 2; ++it) {
    int n0 = (pb + it * 128) * 64;  // token base within (b,s)

    // stage x tile [64][256] fp32 -> bf16 LDS (swizzle: byte ^= (row&7)<<4)
    const f32x4* xsrc = (const f32x4*)(x + (size_t)n0 * C_);
#pragma unroll
    for (int i = 0; i < 16; ++i) {
      int f = t + 256 * i;        // float4 index; row = f>>6
      int row = f >> 6;
      f32x4 v = xsrc[f];
      ushort4 pk;
      pk.x = f2bf(v[0]); pk.y = f2bf(v[1]); pk.z = f2bf(v[2]); pk.w = f2bf(v[3]);
      int off = (f * 8) ^ ((row & 7) << 4);
      *(ushort4*)(xsb + off) = pk;
    }
    __syncthreads();

    // phase 1: [64 tok][256] @ [256][192] -> k|q|v
    // weight B-frags reloaded per-ks from L2, 1-deep pipelined.
    f32x4 acc[4][3];
#pragma unroll
    for (int rf = 0; rf < 4; ++rf)
#pragma unroll
      for (int jj = 0; jj < 3; ++jj) { f32x4 z = {0.f,0.f,0.f,0.f}; acc[rf][jj] = z; }

    bf16x8 bA[3], bB[3];
#pragma unroll
    for (int jj = 0; jj < 3; ++jj)
      bA[jj] = *(const bf16x8*)(wbase + (((size_t)((w*3+jj)*8 + 0))*64 + l)*16);
#pragma unroll
    for (int ks = 0; ks < 8; ++ks) {
      const bf16x8* bc = (ks & 1) ? bB : bA;
      bf16x8* bn = (ks & 1) ? bA : bB;
      if (ks < 7) {
#pragma unroll
        for (int jj = 0; jj < 3; ++jj)
          bn[jj] = *(const bf16x8*)(wbase + (((size_t)((w*3+jj)*8 + ks+1))*64 + l)*16);
      }
      bf16x8 a[4];
#pragma unroll
      for (int rf = 0; rf < 4; ++rf) {
        int row = rf * 16 + l15;
        int off = (row * 512 + ks * 64 + lg * 16) ^ ((row & 7) << 4);
        a[rf] = *(const bf16x8*)(xsb + off);
      }
#pragma unroll
      for (int jj = 0; jj < 3; ++jj)
#pragma unroll
        for (int rf = 0; rf < 4; ++rf)
          acc[rf][jj] = __builtin_amdgcn_mfma_f32_16x16x32_bf16(
              a[rf], bc[jj], acc[rf][jj], 0, 0, 0);
    }
    __syncthreads();   // all xs reads done; overlay region becomes writable

    // fragment processing: k -> exp -> pT + z ; q -> bf16 qs ; v -> vT
#pragma unroll
    for (int jj = 0; jj < 3; ++jj) {
      int gc = w * 48 + jj * 16;
      if (gc < 64) {             // k columns
        int hcol = gc + l15;
        float zl = 0.f;
#pragma unroll
        for (int rf = 0; rf < 4; ++rf)
#pragma unroll
          for (int r = 0; r < 4; ++r) {
            float ev = __expf(acc[rf][jj][r]);
            zl += ev;
            int n = rf * 16 + lg * 4 + r;
            int off = (hcol * 128 + n * 2) ^ ((hcol & 7) << 4);
            *(unsigned short*)(pTb + off) = f2bf(ev);
          }
        zl += __shfl_xor(zl, 16);
        zl += __shfl_xor(zl, 32);
        zacc[jj] += zl;
      } else if (gc < 128) {     // q columns -> bf16 into qs [tok][64]
        int base = gc - 64;
#pragma unroll
        for (int rf = 0; rf < 4; ++rf)
#pragma unroll
          for (int r = 0; r < 4; ++r) {
            int n = rf * 16 + lg * 4 + r;
            int off = (n * 128 + (base + l15) * 2) ^ ((n & 7) << 4);
            *(unsigned short*)(qsb + off) = f2bf(acc[rf][jj][r]);
          }
      } else {                   // v columns
        int dcol = gc - 128 + l15;
#pragma unroll
        for (int rf = 0; rf < 4; ++rf)
#pragma unroll
          for (int r = 0; r < 4; ++r) {
            int n = rf * 16 + lg * 4 + r;
            int off = (dcol * 128 + n * 2) ^ ((dcol & 7) << 4);
            *(unsigned short*)(vTb + off) = f2bf(acc[rf][jj][r]);
          }
      }
    }
    __syncthreads();

    // q readout: coalesced bf16 store to global
    unsigned short* qg = qbuf + ((size_t)bs * N_ + n0) * 64;
#pragma unroll
    for (int r2 = 0; r2 < 2; ++r2) {
      int fi = t + 256 * r2;          // 0..511, 16B chunks of qs
      int n = fi >> 3, c = fi & 7;
      int off = (n * 128 + c * 16) ^ ((n & 7) << 4);
      us8 v = *(const us8*)(qsb + off);
      *(us8*)(qg + (size_t)fi * 8) = v;
    }

    // phase 2: nw[h][d] += P^T V over this tile's 64 tokens
#pragma unroll
    for (int k2 = 0; k2 < 2; ++k2) {
      int hh = w * 16 + l15;
      int aoff = (hh * 128 + (k2 * 32 + lg * 8) * 2) ^ ((hh & 7) << 4);
      bf16x8 a2 = *(const bf16x8*)(pTb + aoff);
#pragma unroll
      for (int j2 = 0; j2 < 4; ++j2) {
        int dd = j2 * 16 + l15;
        int boff = (dd * 128 + (k2 * 32 + lg * 8) * 2) ^ ((dd & 7) << 4);
        bf16x8 b2 = *(const bf16x8*)(vTb + boff);
        nwacc[j2] = __builtin_amdgcn_mfma_f32_16x16x32_bf16(a2, b2, nwacc[j2], 0, 0, 0);
      }
    }
    __syncthreads();   // before next tile's staging overwrites overlay
  }

  // write partials
#pragma unroll
  for (int j2 = 0; j2 < 4; ++j2)
#pragma unroll
    for (int r = 0; r < 4; ++r) {
      int h = w * 16 + lg * 4 + r;
      int d = j2 * 16 + l15;
      pnw[(((size_t)bs * 128 + pb) * 64 + h) * 64 + d] = nwacc[j2][r];
    }
  if (lg == 0) {
#pragma unroll
    for (int jj = 0; jj < 3; ++jj) {
      int gc = w * 48 + jj * 16;
      if (gc < 64) pz[((size_t)bs * 128 + pb) * 64 + gc + l15] = zacc[jj];
    }
  }
}

__global__ __launch_bounds__(256) void kB_reduce(
    const float* __restrict__ pnw, const float* __restrict__ pz,
    float* __restrict__ wfin) {
  int g = blockIdx.x;   // 0..15: idx range [g*256, g*256+256) => h in [g*4, g*4+4)
  int bs = blockIdx.y;  // 0..7
  int t = threadIdx.x;
  int wv = t >> 6, l = t & 63;
  __shared__ float zinv[4];
  int h = g * 4 + wv;
  float z = pz[((size_t)bs * 128 + l) * 64 + h] +
            pz[((size_t)bs * 128 + 64 + l) * 64 + h];
#pragma unroll
  for (int m = 32; m; m >>= 1) z += __shfl_xor(z, m);
  if (l == 0) zinv[wv] = 1.f / z;
  __syncthreads();
  int idx = g * 256 + t;
  float ssum = 0.f;
#pragma unroll 8
  for (int p = 0; p < 128; ++p)
    ssum += pnw[((size_t)bs * 128 + p) * 4096 + idx];
  wfin[(size_t)bs * 4096 + idx] = ssum * zinv[wv];
}

__global__ __launch_bounds__(256) void kC_out(
    const unsigned short* __restrict__ qbuf, const float* __restrict__ wfin,
    float* __restrict__ out) {
  int bs = blockIdx.y, b = bs >> 1, s = bs & 1;
  int t = threadIdx.x;
  int w = t >> 6, l = t & 63;
  int l15 = l & 15, lg = l >> 4;
  int tok0 = blockIdx.x * 64;

  __shared__ __align__(16) char cb[16384];
  char* plb = cb;            // P bf16 [64 tok][64 h], swizzled (8K)
  char* wlb = cb + 8192;     // W^T bf16 [64 d][64 h], swizzled (8K)
  float* ob = (float*)cb;    // out f32 [64 tok][64 d] (16K, aliases after MFMA)

  // 1. load w_{1-s}, transpose to [d][h] bf16 swizzled — ALL 4096 elements
  const float* wsrc = wfin + (size_t)(b * 2 + (1 - s)) * 4096;
#pragma unroll
  for (int rr = 0; rr < 4; ++rr) {
    int fi = t + 256 * rr;        // f32x4 chunk id, [0,1024)
    int h = fi >> 4, d4 = (fi & 15) * 4;
    f32x4 v = *(const f32x4*)(wsrc + h * 64 + d4);
#pragma unroll
    for (int e = 0; e < 4; ++e) {
      int d = d4 + e;
      int off = (d * 128 + h * 2) ^ ((d & 7) << 4);
      *(unsigned short*)(wlb + off) = f2bf(v[e]);
    }
  }

  // 2. q row: exp, quad-reduce sum, normalize, bf16 -> pl
  {
    int tl = t >> 2, p4 = t & 3;
    const unsigned short* qr =
        qbuf + ((size_t)bs * N_ + tok0 + tl) * 64 + p4 * 16;
    us8 u0 = *(const us8*)(qr);
    us8 u1 = *(const us8*)(qr + 8);
    float e[16]; float sum = 0.f;
#pragma unroll
    for (int i = 0; i < 8; ++i) { e[i] = __expf(bf2f(u0[i])); sum += e[i]; }
#pragma unroll
    for (int i = 0; i < 8; ++i) { e[8+i] = __expf(bf2f(u1[i])); sum += e[8+i]; }
    sum += __shfl_xor(sum, 1);
    sum += __shfl_xor(sum, 2);
    float inv = 1.f / sum;
    us8 p0, p1;
#pragma unroll
    for (int i = 0; i < 8; ++i) { p0[i] = f2bf(e[i] * inv); p1[i] = f2bf(e[8+i] * inv); }
    int off = (tl * 128 + p4 * 32) ^ ((tl & 7) << 4);
    *(us8*)(plb + off) = p0;
    *(us8*)(plb + (off ^ 16)) = p1;   // +16 within same 32B chunk: XOR-safe since p4*32 has bit4=0
  }
  __syncthreads();

  // 3. out[64 tok][64 d] = P @ W^T' : 2 K-steps of 16x16x32 MFMA
  f32x4 acc[4];
#pragma unroll
  for (int rf = 0; rf < 4; ++rf) { f32x4 z = {0.f,0.f,0.f,0.f}; acc[rf] = z; }
#pragma unroll
  for (int k2 = 0; k2 < 2; ++k2) {
    int dd = w * 16 + l15;
    int boff = (dd * 128 + (k2 * 32 + lg * 8) * 2) ^ ((dd & 7) << 4);
    bf16x8 bfrag = *(const bf16x8*)(wlb + boff);
#pragma unroll
    for (int rf = 0; rf < 4; ++rf) {
      int row = rf * 16 + l15;
      int aoff = (row * 128 + (k2 * 32 + lg * 8) * 2) ^ ((row & 7) << 4);
      bf16x8 afrag = *(const bf16x8*)(plb + aoff);
      acc[rf] = __builtin_amdgcn_mfma_f32_16x16x32_bf16(afrag, bfrag, acc[rf], 0, 0, 0);
    }
  }
  __syncthreads();   // pl/wl dead; ob takes over

  // 4. fragments -> ob
#pragma unroll
  for (int rf = 0; rf < 4; ++rf)
#pragma unroll
    for (int r = 0; r < 4; ++r) {
      int tok = rf * 16 + lg * 4 + r;
      int d = w * 16 + l15;
      ob[tok * 64 + d] = acc[rf][r];
    }
  __syncthreads();

  // 5. coalesced f32x4 store
  float* outp = out + (size_t)s * ((size_t)B_ * N_ * 64) +
                ((size_t)b * N_ + tok0) * 64;
#pragma unroll
  for (int r2 = 0; r2 < 4; ++r2) {
    int fi = t + 256 * r2;   // 0..1023 f32x4 chunks
    ((f32x4*)outp)[fi] = ((const f32x4*)ob)[fi];
  }
}

extern "C" void kernel_launch(void* const* d_in, const int* in_sizes, int n_in,
                              void* d_out, int out_size, void* d_ws, size_t ws_size,
                              hipStream_t stream) {
  const float* x0  = (const float*)d_in[0];
  const float* x1  = (const float*)d_in[1];
  const float* Wk0 = (const float*)d_in[2];
  const float* Wk1 = (const float*)d_in[3];
  const float* Wq0 = (const float*)d_in[4];
  const float* Wq1 = (const float*)d_in[5];
  const float* Wv0 = (const float*)d_in[6];
  const float* Wv1 = (const float*)d_in[7];
  float* out = (float*)d_out;
  char* wsb = (char*)d_ws;
  unsigned short* wpack = (unsigned short*)(wsb + WPACK_OFF);
  unsigned short* qbuf  = (unsigned short*)(wsb + Q_OFF);
  float* pnw  = (float*)(wsb + PNW_OFF);
  float* pz   = (float*)(wsb + PZ_OFF);
  float* wfin = (float*)(wsb + WFIN_OFF);

  kW_pack<<<dim3(384), dim3(256), 0, stream>>>(Wk0, Wk1, Wq0, Wq1, Wv0, Wv1, wpack);
  kA_proj<<<dim3(128, 8), dim3(256), 0, stream>>>(x0, x1, wpack, qbuf, pnw, pz);
  kB_reduce<<<dim3(16, 8), dim3(256), 0, stream>>>(pnw, pz, wfin);
  kC_out<<<dim3(256, 8), dim3(256), 0, stream>>>(qbuf, wfin, out);
}

// Round 4
// 140.366 us; speedup vs baseline: 1.8612x; 1.8612x over previous
//
#include <hip/hip_runtime.h>

// EfficientCrossAttentionHead: B=4, N=16384, C=256, H=64, fp32 in/out.
//   kW_pack : weights -> bf16 MFMA B-fragment layout in ws
//   kA_proj : 8-wave blocks; x -> (k,q,v) via MFMA; q -> ws bf16 coalesced;
//             per-block partial (sum exp(k)*v, sum exp(k))
//   kB_reduce: partials -> w[bs][64][64] = (sum e*v)/Z
//   kC_out  : out = softmax_row(q_s) @ w_{1-s}  (MFMA, bf16 in / f32 acc)
// ws usage ~25.8 MB.

#define B_ 4
#define N_ 16384
#define C_ 256

typedef float f32x4 __attribute__((ext_vector_type(4)));
typedef __bf16 bf16x8 __attribute__((ext_vector_type(8)));
typedef unsigned short us8 __attribute__((ext_vector_type(8)));

__device__ __forceinline__ unsigned short f2bf(float f) {
  union { float f; unsigned u; } v; v.f = f;
  return (unsigned short)((v.u + 0x7FFFu + ((v.u >> 16) & 1u)) >> 16);
}
__device__ __forceinline__ float bf2f(unsigned short h) {
  union { unsigned u; float f; } v; v.u = ((unsigned)h) << 16;
  return v.f;
}

// ws byte offsets
#define WPACK_OFF 0u           // [2][12][8][64][8] bf16 = 196608 B
#define Q_OFF     262144u      // q logits bf16 [8][16384][64] = 16 MB
#define PNW_OFF   17039360u    // partial nw [8][64][4096] f32 = 8 MB
#define PZ_OFF    25427968u    // partial z  [8][128][64]  f32 = 256 KB
#define WFIN_OFF  25690112u    // w final [8][4096] f32 = 128 KB

__global__ __launch_bounds__(256) void kW_pack(
    const float* __restrict__ Wk0, const float* __restrict__ Wk1,
    const float* __restrict__ Wq0, const float* __restrict__ Wq1,
    const float* __restrict__ Wv0, const float* __restrict__ Wv1,
    unsigned short* __restrict__ wpack) {
  int t = blockIdx.x * 256 + threadIdx.x;  // [0, 98304)
  int i = t & 7;
  int lane = (t >> 3) & 63;
  int q = t >> 9;            // [0,192)
  int ks = q & 7;
  int sj = q >> 3;           // [0,24)
  int s = sj / 12;
  int j = sj - s * 12;       // col-frag 0..11 (k:0-3, q:4-7, v:8-11)
  int gc = 16 * j + (lane & 15);
  int c = 32 * ks + ((lane >> 4) << 3) + i;
  int m = gc >> 6, row = gc & 63;
  const float* W;
  if (s == 0) W = (m == 0) ? Wk0 : (m == 1) ? Wq0 : Wv0;
  else        W = (m == 0) ? Wk1 : (m == 1) ? Wq1 : Wv1;
  wpack[t] = f2bf(W[row * 256 + c]);
}

__global__ __launch_bounds__(512, 4) void kA_proj(
    const float* __restrict__ x0, const float* __restrict__ x1,
    const unsigned short* __restrict__ wpack,
    unsigned short* __restrict__ qbuf, float* __restrict__ pnw,
    float* __restrict__ pz) {
  int slot = blockIdx.x;     // 0..63 partial slot
  int bs = blockIdx.y;       // 0..7 : b = bs>>1, s = bs&1
  int b = bs >> 1, s = bs & 1;
  const float* x = (s ? x1 : x0) + (size_t)b * N_ * C_;
  int t = threadIdx.x;       // 0..511
  int w = t >> 6;            // wave 0..7
  int l = t & 63;
  int l15 = l & 15, lg = l >> 4;
  int wr = w >> 2, wc = w & 3;   // phase-1 role: rows [32wr,32wr+32), cols j in {wc, wc+4, wc+8}
  int hf = w >> 1, dp = w & 1;   // phase-2 role: h-frag hf, d-frags {2dp, 2dp+1}

  // 32 KB: x tile [64][256] bf16 swizzled; after phase 1, first 24 KB is
  // overlaid with pT (8K) | vT (8K) | qs (8K).
  __shared__ __align__(16) char xsb[32768];
  char* pTb = xsb;
  char* vTb = xsb + 8192;
  char* qsb = xsb + 16384;

  const char* wbase = (const char*)wpack + (size_t)s * 12 * 8 * 64 * 16;

  f32x4 nwacc[2];
#pragma unroll
  for (int j2 = 0; j2 < 2; ++j2) { f32x4 z = {0.f,0.f,0.f,0.f}; nwacc[j2] = z; }
  float zacc = 0.f;

  for (int it = 0; it < 4; ++it) {
    int n0 = (slot + it * 64) * 64;  // token base within (b,s)

    // stage x tile [64][256] fp32 -> bf16 LDS (swizzle: byte ^= (row&7)<<4)
    // 4096 f32x4 chunks, 8 per thread, in 2 groups of 4 to bound live regs.
    const f32x4* xsrc = (const f32x4*)(x + (size_t)n0 * C_);
    for (int g2 = 0; g2 < 2; ++g2) {
#pragma unroll
      for (int i = 0; i < 4; ++i) {
        int f = t + 512 * (g2 * 4 + i);  // chunk id; row = f>>6
        int row = f >> 6;
        f32x4 v = xsrc[f];
        ushort4 pk;
        pk.x = f2bf(v[0]); pk.y = f2bf(v[1]); pk.z = f2bf(v[2]); pk.w = f2bf(v[3]);
        int off = (f * 8) ^ ((row & 7) << 4);
        *(ushort4*)(xsb + off) = pk;
      }
    }
    __syncthreads();

    // phase 1: [64 tok][256] @ [256][192] -> k|q|v
    // weight B-frags reloaded per-ks from L2, 1-deep pipelined.
    f32x4 acc[2][3];
#pragma unroll
    for (int rf = 0; rf < 2; ++rf)
#pragma unroll
      for (int jj = 0; jj < 3; ++jj) { f32x4 z = {0.f,0.f,0.f,0.f}; acc[rf][jj] = z; }

    bf16x8 bA[3], bB[3];
#pragma unroll
    for (int jj = 0; jj < 3; ++jj)
      bA[jj] = *(const bf16x8*)(wbase + (((size_t)((wc + 4*jj)*8 + 0))*64 + l)*16);
#pragma unroll
    for (int ks = 0; ks < 8; ++ks) {
      const bf16x8* bc = (ks & 1) ? bB : bA;
      bf16x8* bn = (ks & 1) ? bA : bB;
      if (ks < 7) {
#pragma unroll
        for (int jj = 0; jj < 3; ++jj)
          bn[jj] = *(const bf16x8*)(wbase + (((size_t)((wc + 4*jj)*8 + ks+1))*64 + l)*16);
      }
      bf16x8 a[2];
#pragma unroll
      for (int rf = 0; rf < 2; ++rf) {
        int row = (wr * 2 + rf) * 16 + l15;
        int off = (row * 512 + ks * 64 + lg * 16) ^ ((row & 7) << 4);
        a[rf] = *(const bf16x8*)(xsb + off);
      }
#pragma unroll
      for (int jj = 0; jj < 3; ++jj)
#pragma unroll
        for (int rf = 0; rf < 2; ++rf)
          acc[rf][jj] = __builtin_amdgcn_mfma_f32_16x16x32_bf16(
              a[rf], bc[jj], acc[rf][jj], 0, 0, 0);
    }
    __syncthreads();   // all xs reads done; overlay region becomes writable

    // fragment processing. token idx within tile: n = (wr*2+rf)*16 + lg*4 + r
    // k (jj=0): exp -> pT[h][n] + z
    {
      int hcol = wc * 16 + l15;
      float zl = 0.f;
#pragma unroll
      for (int rf = 0; rf < 2; ++rf)
#pragma unroll
        for (int r = 0; r < 4; ++r) {
          float ev = __expf(acc[rf][0][r]);
          zl += ev;
          int n = (wr * 2 + rf) * 16 + lg * 4 + r;
          int off = (hcol * 128 + n * 2) ^ ((hcol & 7) << 4);
          *(unsigned short*)(pTb + off) = f2bf(ev);
        }
      zl += __shfl_xor(zl, 16);
      zl += __shfl_xor(zl, 32);
      zacc += zl;
    }
    // q (jj=1): bf16 into qs [n][64 h]
    {
#pragma unroll
      for (int rf = 0; rf < 2; ++rf)
#pragma unroll
        for (int r = 0; r < 4; ++r) {
          int n = (wr * 2 + rf) * 16 + lg * 4 + r;
          int off = (n * 128 + (wc * 16 + l15) * 2) ^ ((n & 7) << 4);
          *(unsigned short*)(qsb + off) = f2bf(acc[rf][1][r]);
        }
    }
    // v (jj=2): vT[d][n]
    {
      int dcol = wc * 16 + l15;
#pragma unroll
      for (int rf = 0; rf < 2; ++rf)
#pragma unroll
        for (int r = 0; r < 4; ++r) {
          int n = (wr * 2 + rf) * 16 + lg * 4 + r;
          int off = (dcol * 128 + n * 2) ^ ((dcol & 7) << 4);
          *(unsigned short*)(vTb + off) = f2bf(acc[rf][2][r]);
        }
    }
    __syncthreads();

    // q readout: coalesced bf16 store to global (512 chunks, 1 per thread)
    {
      unsigned short* qg = qbuf + ((size_t)bs * N_ + n0) * 64;
      int n = t >> 3, c = t & 7;
      int off = (n * 128 + c * 16) ^ ((n & 7) << 4);
      us8 v = *(const us8*)(qsb + off);
      *(us8*)(qg + (size_t)t * 8) = v;
    }

    // phase 2: nw[h][d] += P^T V over this tile's 64 tokens
#pragma unroll
    for (int k2 = 0; k2 < 2; ++k2) {
      int hh = hf * 16 + l15;
      int aoff = (hh * 128 + (k2 * 32 + lg * 8) * 2) ^ ((hh & 7) << 4);
      bf16x8 a2 = *(const bf16x8*)(pTb + aoff);
#pragma unroll
      for (int df = 0; df < 2; ++df) {
        int dd = (dp * 2 + df) * 16 + l15;
        int boff = (dd * 128 + (k2 * 32 + lg * 8) * 2) ^ ((dd & 7) << 4);
        bf16x8 b2 = *(const bf16x8*)(vTb + boff);
        nwacc[df] = __builtin_amdgcn_mfma_f32_16x16x32_bf16(a2, b2, nwacc[df], 0, 0, 0);
      }
    }
    __syncthreads();   // before next tile's staging overwrites overlay
  }

  // write partials
#pragma unroll
  for (int df = 0; df < 2; ++df)
#pragma unroll
    for (int r = 0; r < 4; ++r) {
      int h = hf * 16 + lg * 4 + r;
      int d = (dp * 2 + df) * 16 + l15;
      pnw[(((size_t)bs * 64 + slot) * 64 + h) * 64 + d] = nwacc[df][r];
    }
  if (lg == 0)
    pz[(((size_t)bs * 64 + slot) * 2 + wr) * 64 + wc * 16 + l15] = zacc;
}

__global__ __launch_bounds__(256) void kB_reduce(
    const float* __restrict__ pnw, const float* __restrict__ pz,
    float* __restrict__ wfin) {
  int g = blockIdx.x;   // 0..15: idx range [g*256, g*256+256) => h in [g*4, g*4+4)
  int bs = blockIdx.y;  // 0..7
  int t = threadIdx.x;
  int wv = t >> 6, l = t & 63;
  __shared__ float zinv[4];
  int h = g * 4 + wv;
  float z = pz[((size_t)bs * 128 + l) * 64 + h] +
            pz[((size_t)bs * 128 + 64 + l) * 64 + h];
#pragma unroll
  for (int m = 32; m; m >>= 1) z += __shfl_xor(z, m);
  if (l == 0) zinv[wv] = 1.f / z;
  __syncthreads();
  int idx = g * 256 + t;
  float ssum = 0.f;
#pragma unroll 8
  for (int p = 0; p < 64; ++p)
    ssum += pnw[((size_t)bs * 64 + p) * 4096 + idx];
  wfin[(size_t)bs * 4096 + idx] = ssum * zinv[wv];
}

__global__ __launch_bounds__(256) void kC_out(
    const unsigned short* __restrict__ qbuf, const float* __restrict__ wfin,
    float* __restrict__ out) {
  int bs = blockIdx.y, b = bs >> 1, s = bs & 1;
  int t = threadIdx.x;
  int w = t >> 6, l = t & 63;
  int l15 = l & 15, lg = l >> 4;
  int tok0 = blockIdx.x * 64;

  __shared__ __align__(16) char cb[16384];
  char* plb = cb;            // P bf16 [64 tok][64 h], swizzled (8K)
  char* wlb = cb + 8192;     // W^T bf16 [64 d][64 h], swizzled (8K)
  float* ob = (float*)cb;    // out f32 [64 tok][64 d] (16K, aliases after MFMA)

  // 1. load w_{1-s}, transpose to [d][h] bf16 swizzled — all 4096 elements
  const float* wsrc = wfin + (size_t)(b * 2 + (1 - s)) * 4096;
#pragma unroll
  for (int rr = 0; rr < 4; ++rr) {
    int fi = t + 256 * rr;        // f32x4 chunk id, [0,1024)
    int h = fi >> 4, d4 = (fi & 15) * 4;
    f32x4 v = *(const f32x4*)(wsrc + h * 64 + d4);
#pragma unroll
    for (int e = 0; e < 4; ++e) {
      int d = d4 + e;
      int off = (d * 128 + h * 2) ^ ((d & 7) << 4);
      *(unsigned short*)(wlb + off) = f2bf(v[e]);
    }
  }

  // 2. q row: exp, quad-reduce sum, normalize, bf16 -> pl
  {
    int tl = t >> 2, p4 = t & 3;
    const unsigned short* qr =
        qbuf + ((size_t)bs * N_ + tok0 + tl) * 64 + p4 * 16;
    us8 u0 = *(const us8*)(qr);
    us8 u1 = *(const us8*)(qr + 8);
    float e[16]; float sum = 0.f;
#pragma unroll
    for (int i = 0; i < 8; ++i) { e[i] = __expf(bf2f(u0[i])); sum += e[i]; }
#pragma unroll
    for (int i = 0; i < 8; ++i) { e[8+i] = __expf(bf2f(u1[i])); sum += e[8+i]; }
    sum += __shfl_xor(sum, 1);
    sum += __shfl_xor(sum, 2);
    float inv = 1.f / sum;
    us8 p0, p1;
#pragma unroll
    for (int i = 0; i < 8; ++i) { p0[i] = f2bf(e[i] * inv); p1[i] = f2bf(e[8+i] * inv); }
    int off = (tl * 128 + p4 * 32) ^ ((tl & 7) << 4);
    *(us8*)(plb + off) = p0;
    *(us8*)(plb + (off ^ 16)) = p1;   // +16 within same 32B chunk (p4*32 has bit4=0)
  }
  __syncthreads();

  // 3. out[64 tok][64 d] = P @ W^T' : 2 K-steps of 16x16x32 MFMA
  f32x4 acc[4];
#pragma unroll
  for (int rf = 0; rf < 4; ++rf) { f32x4 z = {0.f,0.f,0.f,0.f}; acc[rf] = z; }
#pragma unroll
  for (int k2 = 0; k2 < 2; ++k2) {
    int dd = w * 16 + l15;
    int boff = (dd * 128 + (k2 * 32 + lg * 8) * 2) ^ ((dd & 7) << 4);
    bf16x8 bfrag = *(const bf16x8*)(wlb + boff);
#pragma unroll
    for (int rf = 0; rf < 4; ++rf) {
      int row = rf * 16 + l15;
      int aoff = (row * 128 + (k2 * 32 + lg * 8) * 2) ^ ((row & 7) << 4);
      bf16x8 afrag = *(const bf16x8*)(plb + aoff);
      acc[rf] = __builtin_amdgcn_mfma_f32_16x16x32_bf16(afrag, bfrag, acc[rf], 0, 0, 0);
    }
  }
  __syncthreads();   // pl/wl dead; ob takes over

  // 4. fragments -> ob
#pragma unroll
  for (int rf = 0; rf < 4; ++rf)
#pragma unroll
    for (int r = 0; r < 4; ++r) {
      int tok = rf * 16 + lg * 4 + r;
      int d = w * 16 + l15;
      ob[tok * 64 + d] = acc[rf][r];
    }
  __syncthreads();

  // 5. coalesced f32x4 store
  float* outp = out + (size_t)s * ((size_t)B_ * N_ * 64) +
                ((size_t)b * N_ + tok0) * 64;
#pragma unroll
  for (int r2 = 0; r2 < 4; ++r2) {
    int fi = t + 256 * r2;   // 0..1023 f32x4 chunks
    ((f32x4*)outp)[fi] = ((const f32x4*)ob)[fi];
  }
}

extern "C" void kernel_launch(void* const* d_in, const int* in_sizes, int n_in,
                              void* d_out, int out_size, void* d_ws, size_t ws_size,
                              hipStream_t stream) {
  const float* x0  = (const float*)d_in[0];
  const float* x1  = (const float*)d_in[1];
  const float* Wk0 = (const float*)d_in[2];
  const float* Wk1 = (const float*)d_in[3];
  const float* Wq0 = (const float*)d_in[4];
  const float* Wq1 = (const float*)d_in[5];
  const float* Wv0 = (const float*)d_in[6];
  const float* Wv1 = (const float*)d_in[7];
  float* out = (float*)d_out;
  char* wsb = (char*)d_ws;
  unsigned short* wpack = (unsigned short*)(wsb + WPACK_OFF);
  unsigned short* qbuf  = (unsigned short*)(wsb + Q_OFF);
  float* pnw  = (float*)(wsb + PNW_OFF);
  float* pz   = (float*)(wsb + PZ_OFF);
  float* wfin = (float*)(wsb + WFIN_OFF);

  kW_pack<<<dim3(384), dim3(256), 0, stream>>>(Wk0, Wk1, Wq0, Wq1, Wv0, Wv1, wpack);
  kA_proj<<<dim3(64, 8), dim3(512), 0, stream>>>(x0, x1, wpack, qbuf, pnw, pz);
  kB_reduce<<<dim3(16, 8), dim3(256), 0, stream>>>(pnw, pz, wfin);
  kC_out<<<dim3(256, 8), dim3(256), 0, stream>>>(qbuf, wfin, out);
}

// Round 5
// 61.122 us; speedup vs baseline: 4.2742x; 2.2965x over previous
//
#include <hip/hip_runtime.h>

// EfficientCrossAttentionHead: B=4, N=16384, C=256, H=64, fp32 in/out.
//   kW_pack : weights -> bf16 MFMA B-fragment layout in ws
//   kA_proj : 8-wave blocks; x -> (k,q,v) via MFMA; q -> ws bf16 coalesced;
//             per-block partial (sum exp(k)*v, sum exp(k))
//   kB_reduce: partials -> w[bs][64][64] = (sum e*v)/Z
//   kC_out  : out = softmax_row(q_s) @ w_{1-s}  (MFMA, bf16 in / f32 acc)
// ws usage ~25.8 MB.

#define B_ 4
#define N_ 16384
#define C_ 256

typedef float f32x4 __attribute__((ext_vector_type(4)));
typedef __bf16 bf16x8 __attribute__((ext_vector_type(8)));
typedef unsigned short us8 __attribute__((ext_vector_type(8)));

__device__ __forceinline__ unsigned short f2bf(float f) {
  union { float f; unsigned u; } v; v.f = f;
  return (unsigned short)((v.u + 0x7FFFu + ((v.u >> 16) & 1u)) >> 16);
}
__device__ __forceinline__ float bf2f(unsigned short h) {
  union { unsigned u; float f; } v; v.u = ((unsigned)h) << 16;
  return v.f;
}

// ws byte offsets
#define WPACK_OFF 0u           // [2][12][8][64][8] bf16 = 196608 B
#define Q_OFF     262144u      // q logits bf16 [8][16384][64] = 16 MB
#define PNW_OFF   17039360u    // partial nw [8][64][4096] f32 = 8 MB
#define PZ_OFF    25427968u    // partial z  [8][128][64]  f32 = 256 KB
#define WFIN_OFF  25690112u    // w final [8][4096] f32 = 128 KB

__global__ __launch_bounds__(256) void kW_pack(
    const float* __restrict__ Wk0, const float* __restrict__ Wk1,
    const float* __restrict__ Wq0, const float* __restrict__ Wq1,
    const float* __restrict__ Wv0, const float* __restrict__ Wv1,
    unsigned short* __restrict__ wpack) {
  int t = blockIdx.x * 256 + threadIdx.x;  // [0, 98304)
  int i = t & 7;
  int lane = (t >> 3) & 63;
  int q = t >> 9;            // [0,192)
  int ks = q & 7;
  int sj = q >> 3;           // [0,24)
  int s = sj / 12;
  int j = sj - s * 12;       // col-frag 0..11 (k:0-3, q:4-7, v:8-11)
  int gc = 16 * j + (lane & 15);
  int c = 32 * ks + ((lane >> 4) << 3) + i;
  int m = gc >> 6, row = gc & 63;
  const float* W;
  if (s == 0) W = (m == 0) ? Wk0 : (m == 1) ? Wq0 : Wv0;
  else        W = (m == 0) ? Wk1 : (m == 1) ? Wq1 : Wv1;
  wpack[t] = f2bf(W[row * 256 + c]);
}

__global__ __launch_bounds__(512, 2) void kA_proj(
    const float* __restrict__ x0, const float* __restrict__ x1,
    const unsigned short* __restrict__ wpack,
    unsigned short* __restrict__ qbuf, float* __restrict__ pnw,
    float* __restrict__ pz) {
  int slot = blockIdx.x;     // 0..63 partial slot
  int bs = blockIdx.y;       // 0..7 : b = bs>>1, s = bs&1
  int b = bs >> 1, s = bs & 1;
  const float* x = (s ? x1 : x0) + (size_t)b * N_ * C_;
  int t = threadIdx.x;       // 0..511
  int w = t >> 6;            // wave 0..7
  int l = t & 63;
  int l15 = l & 15, lg = l >> 4;
  int wr = w >> 2, wc = w & 3;   // phase-1 role: rows [32wr,32wr+32), cols j in {wc, wc+4, wc+8}
  int hf = w >> 1, dp = w & 1;   // phase-2 role: h-frag hf, d-frags {2dp, 2dp+1}

  // 32 KB: x tile [64][256] bf16 swizzled; after phase 1, first 24 KB is
  // overlaid with pT (8K) | vT (8K) | qs (8K).
  __shared__ __align__(16) char xsb[32768];
  char* pTb = xsb;
  char* vTb = xsb + 8192;
  char* qsb = xsb + 16384;

  const char* wbase = (const char*)wpack + (size_t)s * 12 * 8 * 64 * 16;

  f32x4 nwacc[2];
#pragma unroll
  for (int j2 = 0; j2 < 2; ++j2) { f32x4 z = {0.f,0.f,0.f,0.f}; nwacc[j2] = z; }
  float zacc = 0.f;

  for (int it = 0; it < 4; ++it) {
    int n0 = (slot + it * 64) * 64;  // token base within (b,s)

    // stage x tile [64][256] fp32 -> bf16 LDS (swizzle: byte ^= (row&7)<<4)
    // 4096 f32x4 chunks, 8 per thread, in 2 groups of 4 to bound live regs.
    const f32x4* xsrc = (const f32x4*)(x + (size_t)n0 * C_);
#pragma unroll 1
    for (int g2 = 0; g2 < 2; ++g2) {
#pragma unroll
      for (int i = 0; i < 4; ++i) {
        int f = t + 512 * (g2 * 4 + i);  // chunk id; row = f>>6
        int row = f >> 6;
        f32x4 v = xsrc[f];
        ushort4 pk;
        pk.x = f2bf(v[0]); pk.y = f2bf(v[1]); pk.z = f2bf(v[2]); pk.w = f2bf(v[3]);
        int off = (f * 8) ^ ((row & 7) << 4);
        *(ushort4*)(xsb + off) = pk;
      }
    }
    __syncthreads();

    // phase 1: [64 tok][256] @ [256][192] -> k|q|v
    // weight B-frags reloaded per-ks from L2, 1-deep pipelined.
    f32x4 acc[2][3];
#pragma unroll
    for (int rf = 0; rf < 2; ++rf)
#pragma unroll
      for (int jj = 0; jj < 3; ++jj) { f32x4 z = {0.f,0.f,0.f,0.f}; acc[rf][jj] = z; }

    bf16x8 bA[3], bB[3];
#pragma unroll
    for (int jj = 0; jj < 3; ++jj)
      bA[jj] = *(const bf16x8*)(wbase + (((size_t)((wc + 4*jj)*8 + 0))*64 + l)*16);
#pragma unroll
    for (int ks = 0; ks < 8; ++ks) {
      const bf16x8* bc = (ks & 1) ? bB : bA;
      bf16x8* bn = (ks & 1) ? bA : bB;
      if (ks < 7) {
#pragma unroll
        for (int jj = 0; jj < 3; ++jj)
          bn[jj] = *(const bf16x8*)(wbase + (((size_t)((wc + 4*jj)*8 + ks+1))*64 + l)*16);
      }
      bf16x8 a[2];
#pragma unroll
      for (int rf = 0; rf < 2; ++rf) {
        int row = (wr * 2 + rf) * 16 + l15;
        int off = (row * 512 + ks * 64 + lg * 16) ^ ((row & 7) << 4);
        a[rf] = *(const bf16x8*)(xsb + off);
      }
#pragma unroll
      for (int jj = 0; jj < 3; ++jj)
#pragma unroll
        for (int rf = 0; rf < 2; ++rf)
          acc[rf][jj] = __builtin_amdgcn_mfma_f32_16x16x32_bf16(
              a[rf], bc[jj], acc[rf][jj], 0, 0, 0);
    }
    __syncthreads();   // all xs reads done; overlay region becomes writable

    // fragment processing. token idx within tile: n = (wr*2+rf)*16 + lg*4 + r
    // k (jj=0): exp -> pT[h][n] + z
    {
      int hcol = wc * 16 + l15;
      float zl = 0.f;
#pragma unroll
      for (int rf = 0; rf < 2; ++rf)
#pragma unroll
        for (int r = 0; r < 4; ++r) {
          float ev = __expf(acc[rf][0][r]);
          zl += ev;
          int n = (wr * 2 + rf) * 16 + lg * 4 + r;
          int off = (hcol * 128 + n * 2) ^ ((hcol & 7) << 4);
          *(unsigned short*)(pTb + off) = f2bf(ev);
        }
      zl += __shfl_xor(zl, 16);
      zl += __shfl_xor(zl, 32);
      zacc += zl;
    }
    // q (jj=1): bf16 into qs [n][64 h]
    {
#pragma unroll
      for (int rf = 0; rf < 2; ++rf)
#pragma unroll
        for (int r = 0; r < 4; ++r) {
          int n = (wr * 2 + rf) * 16 + lg * 4 + r;
          int off = (n * 128 + (wc * 16 + l15) * 2) ^ ((n & 7) << 4);
          *(unsigned short*)(qsb + off) = f2bf(acc[rf][1][r]);
        }
    }
    // v (jj=2): vT[d][n]
    {
      int dcol = wc * 16 + l15;
#pragma unroll
      for (int rf = 0; rf < 2; ++rf)
#pragma unroll
        for (int r = 0; r < 4; ++r) {
          int n = (wr * 2 + rf) * 16 + lg * 4 + r;
          int off = (dcol * 128 + n * 2) ^ ((dcol & 7) << 4);
          *(unsigned short*)(vTb + off) = f2bf(acc[rf][2][r]);
        }
    }
    __syncthreads();

    // q readout: coalesced bf16 store to global (512 chunks, 1 per thread)
    {
      unsigned short* qg = qbuf + ((size_t)bs * N_ + n0) * 64;
      int n = t >> 3, c = t & 7;
      int off = (n * 128 + c * 16) ^ ((n & 7) << 4);
      us8 v = *(const us8*)(qsb + off);
      *(us8*)(qg + (size_t)t * 8) = v;
    }

    // phase 2: nw[h][d] += P^T V over this tile's 64 tokens
#pragma unroll
    for (int k2 = 0; k2 < 2; ++k2) {
      int hh = hf * 16 + l15;
      int aoff = (hh * 128 + (k2 * 32 + lg * 8) * 2) ^ ((hh & 7) << 4);
      bf16x8 a2 = *(const bf16x8*)(pTb + aoff);
#pragma unroll
      for (int df = 0; df < 2; ++df) {
        int dd = (dp * 2 + df) * 16 + l15;
        int boff = (dd * 128 + (k2 * 32 + lg * 8) * 2) ^ ((dd & 7) << 4);
        bf16x8 b2 = *(const bf16x8*)(vTb + boff);
        nwacc[df] = __builtin_amdgcn_mfma_f32_16x16x32_bf16(a2, b2, nwacc[df], 0, 0, 0);
      }
    }
    __syncthreads();   // before next tile's staging overwrites overlay
  }

  // write partials
#pragma unroll
  for (int df = 0; df < 2; ++df)
#pragma unroll
    for (int r = 0; r < 4; ++r) {
      int h = hf * 16 + lg * 4 + r;
      int d = (dp * 2 + df) * 16 + l15;
      pnw[(((size_t)bs * 64 + slot) * 64 + h) * 64 + d] = nwacc[df][r];
    }
  if (lg == 0)
    pz[(((size_t)bs * 64 + slot) * 2 + wr) * 64 + wc * 16 + l15] = zacc;
}

__global__ __launch_bounds__(256) void kB_reduce(
    const float* __restrict__ pnw, const float* __restrict__ pz,
    float* __restrict__ wfin) {
  int g = blockIdx.x;   // 0..15: idx range [g*256, g*256+256) => h in [g*4, g*4+4)
  int bs = blockIdx.y;  // 0..7
  int t = threadIdx.x;
  int wv = t >> 6, l = t & 63;
  __shared__ float zinv[4];
  int h = g * 4 + wv;
  float z = pz[((size_t)bs * 128 + l) * 64 + h] +
            pz[((size_t)bs * 128 + 64 + l) * 64 + h];
#pragma unroll
  for (int m = 32; m; m >>= 1) z += __shfl_xor(z, m);
  if (l == 0) zinv[wv] = 1.f / z;
  __syncthreads();
  int idx = g * 256 + t;
  float ssum = 0.f;
#pragma unroll 8
  for (int p = 0; p < 64; ++p)
    ssum += pnw[((size_t)bs * 64 + p) * 4096 + idx];
  wfin[(size_t)bs * 4096 + idx] = ssum * zinv[wv];
}

__global__ __launch_bounds__(256) void kC_out(
    const unsigned short* __restrict__ qbuf, const float* __restrict__ wfin,
    float* __restrict__ out) {
  int bs = blockIdx.y, b = bs >> 1, s = bs & 1;
  int t = threadIdx.x;
  int w = t >> 6, l = t & 63;
  int l15 = l & 15, lg = l >> 4;
  int tok0 = blockIdx.x * 64;

  __shared__ __align__(16) char cb[16384];
  char* plb = cb;            // P bf16 [64 tok][64 h], swizzled (8K)
  char* wlb = cb + 8192;     // W^T bf16 [64 d][64 h], swizzled (8K)
  float* ob = (float*)cb;    // out f32 [64 tok][64 d] (16K, aliases after MFMA)

  // 1. load w_{1-s}, transpose to [d][h] bf16 swizzled — all 4096 elements
  const float* wsrc = wfin + (size_t)(b * 2 + (1 - s)) * 4096;
#pragma unroll
  for (int rr = 0; rr < 4; ++rr) {
    int fi = t + 256 * rr;        // f32x4 chunk id, [0,1024)
    int h = fi >> 4, d4 = (fi & 15) * 4;
    f32x4 v = *(const f32x4*)(wsrc + h * 64 + d4);
#pragma unroll
    for (int e = 0; e < 4; ++e) {
      int d = d4 + e;
      int off = (d * 128 + h * 2) ^ ((d & 7) << 4);
      *(unsigned short*)(wlb + off) = f2bf(v[e]);
    }
  }

  // 2. q row: exp, quad-reduce sum, normalize, bf16 -> pl
  {
    int tl = t >> 2, p4 = t & 3;
    const unsigned short* qr =
        qbuf + ((size_t)bs * N_ + tok0 + tl) * 64 + p4 * 16;
    us8 u0 = *(const us8*)(qr);
    us8 u1 = *(const us8*)(qr + 8);
    float e[16]; float sum = 0.f;
#pragma unroll
    for (int i = 0; i < 8; ++i) { e[i] = __expf(bf2f(u0[i])); sum += e[i]; }
#pragma unroll
    for (int i = 0; i < 8; ++i) { e[8+i] = __expf(bf2f(u1[i])); sum += e[8+i]; }
    sum += __shfl_xor(sum, 1);
    sum += __shfl_xor(sum, 2);
    float inv = 1.f / sum;
    us8 p0, p1;
#pragma unroll
    for (int i = 0; i < 8; ++i) { p0[i] = f2bf(e[i] * inv); p1[i] = f2bf(e[8+i] * inv); }
    int off = (tl * 128 + p4 * 32) ^ ((tl & 7) << 4);
    *(us8*)(plb + off) = p0;
    *(us8*)(plb + (off ^ 16)) = p1;   // +16 within same 32B chunk (p4*32 has bit4=0)
  }
  __syncthreads();

  // 3. out[64 tok][64 d] = P @ W^T' : 2 K-steps of 16x16x32 MFMA
  f32x4 acc[4];
#pragma unroll
  for (int rf = 0; rf < 4; ++rf) { f32x4 z = {0.f,0.f,0.f,0.f}; acc[rf] = z; }
#pragma unroll
  for (int k2 = 0; k2 < 2; ++k2) {
    int dd = w * 16 + l15;
    int boff = (dd * 128 + (k2 * 32 + lg * 8) * 2) ^ ((dd & 7) << 4);
    bf16x8 bfrag = *(const bf16x8*)(wlb + boff);
#pragma unroll
    for (int rf = 0; rf < 4; ++rf) {
      int row = rf * 16 + l15;
      int aoff = (row * 128 + (k2 * 32 + lg * 8) * 2) ^ ((row & 7) << 4);
      bf16x8 afrag = *(const bf16x8*)(plb + aoff);
      acc[rf] = __builtin_amdgcn_mfma_f32_16x16x32_bf16(afrag, bfrag, acc[rf], 0, 0, 0);
    }
  }
  __syncthreads();   // pl/wl dead; ob takes over

  // 4. fragments -> ob
#pragma unroll
  for (int rf = 0; rf < 4; ++rf)
#pragma unroll
    for (int r = 0; r < 4; ++r) {
      int tok = rf * 16 + lg * 4 + r;
      int d = w * 16 + l15;
      ob[tok * 64 + d] = acc[rf][r];
    }
  __syncthreads();

  // 5. coalesced f32x4 store
  float* outp = out + (size_t)s * ((size_t)B_ * N_ * 64) +
                ((size_t)b * N_ + tok0) * 64;
#pragma unroll
  for (int r2 = 0; r2 < 4; ++r2) {
    int fi = t + 256 * r2;   // 0..1023 f32x4 chunks
    ((f32x4*)outp)[fi] = ((const f32x4*)ob)[fi];
  }
}

extern "C" void kernel_launch(void* const* d_in, const int* in_sizes, int n_in,
                              void* d_out, int out_size, void* d_ws, size_t ws_size,
                              hipStream_t stream) {
  const float* x0  = (const float*)d_in[0];
  const float* x1  = (const float*)d_in[1];
  const float* Wk0 = (const float*)d_in[2];
  const float* Wk1 = (const float*)d_in[3];
  const float* Wq0 = (const float*)d_in[4];
  const float* Wq1 = (const float*)d_in[5];
  const float* Wv0 = (const float*)d_in[6];
  const float* Wv1 = (const float*)d_in[7];
  float* out = (float*)d_out;
  char* wsb = (char*)d_ws;
  unsigned short* wpack = (unsigned short*)(wsb + WPACK_OFF);
  unsigned short* qbuf  = (unsigned short*)(wsb + Q_OFF);
  float* pnw  = (float*)(wsb + PNW_OFF);
  float* pz   = (float*)(wsb + PZ_OFF);
  float* wfin = (float*)(wsb + WFIN_OFF);

  kW_pack<<<dim3(384), dim3(256), 0, stream>>>(Wk0, Wk1, Wq0, Wq1, Wv0, Wv1, wpack);
  kA_proj<<<dim3(64, 8), dim3(512), 0, stream>>>(x0, x1, wpack, qbuf, pnw, pz);
  kB_reduce<<<dim3(16, 8), dim3(256), 0, stream>>>(pnw, pz, wfin);
  kC_out<<<dim3(256, 8), dim3(256), 0, stream>>>(qbuf, wfin, out);
}

// Round 6
// 58.784 us; speedup vs baseline: 4.4441x; 1.0398x over previous
//
#include <hip/hip_runtime.h>

// EfficientCrossAttentionHead: B=4, N=16384, C=256, H=64, fp32 in/out.
//   kW_pack : weights -> bf16 MFMA B-fragment layout in ws
//   kA_proj : 8-wave blocks; x -> (k,q,v) via MFMA; q -> ws bf16 coalesced;
//             per-block partial (sum exp(k)*v, sum exp(k));
//             T14 async-stage: next tile's global loads issued before phase 1,
//             converted+written to LDS after phase 2.
//   kB_reduce: partials -> w[bs][64][64] = (sum e*v)/Z
//   kC_out  : out = softmax_row(q_s) @ w_{1-s}  (MFMA, bf16 in / f32 acc)
// ws usage ~25.8 MB.

#define B_ 4
#define N_ 16384
#define C_ 256

typedef float f32x4 __attribute__((ext_vector_type(4)));
typedef __bf16 bf16x8 __attribute__((ext_vector_type(8)));
typedef unsigned short us8 __attribute__((ext_vector_type(8)));

__device__ __forceinline__ unsigned short f2bf(float f) {
  union { float f; unsigned u; } v; v.f = f;
  return (unsigned short)((v.u + 0x7FFFu + ((v.u >> 16) & 1u)) >> 16);
}
__device__ __forceinline__ float bf2f(unsigned short h) {
  union { unsigned u; float f; } v; v.u = ((unsigned)h) << 16;
  return v.f;
}

// ws byte offsets
#define WPACK_OFF 0u           // [2][12][8][64][8] bf16 = 196608 B
#define Q_OFF     262144u      // q logits bf16 [8][16384][64] = 16 MB
#define PNW_OFF   17039360u    // partial nw [8][64][4096] f32 = 8 MB
#define PZ_OFF    25427968u    // partial z  [8][128][64]  f32 = 256 KB
#define WFIN_OFF  25690112u    // w final [8][4096] f32 = 128 KB

__global__ __launch_bounds__(256) void kW_pack(
    const float* __restrict__ Wk0, const float* __restrict__ Wk1,
    const float* __restrict__ Wq0, const float* __restrict__ Wq1,
    const float* __restrict__ Wv0, const float* __restrict__ Wv1,
    unsigned short* __restrict__ wpack) {
  int t = blockIdx.x * 256 + threadIdx.x;  // [0, 98304)
  int i = t & 7;
  int lane = (t >> 3) & 63;
  int q = t >> 9;            // [0,192)
  int ks = q & 7;
  int sj = q >> 3;           // [0,24)
  int s = sj / 12;
  int j = sj - s * 12;       // col-frag 0..11 (k:0-3, q:4-7, v:8-11)
  int gc = 16 * j + (lane & 15);
  int c = 32 * ks + ((lane >> 4) << 3) + i;
  int m = gc >> 6, row = gc & 63;
  const float* W;
  if (s == 0) W = (m == 0) ? Wk0 : (m == 1) ? Wq0 : Wv0;
  else        W = (m == 0) ? Wk1 : (m == 1) ? Wq1 : Wv1;
  wpack[t] = f2bf(W[row * 256 + c]);
}

__global__ __launch_bounds__(512, 2) void kA_proj(
    const float* __restrict__ x0, const float* __restrict__ x1,
    const unsigned short* __restrict__ wpack,
    unsigned short* __restrict__ qbuf, float* __restrict__ pnw,
    float* __restrict__ pz) {
  int slot = blockIdx.x;     // 0..63 partial slot
  int bs = blockIdx.y;       // 0..7 : b = bs>>1, s = bs&1
  int b = bs >> 1, s = bs & 1;
  const float* x = (s ? x1 : x0) + (size_t)b * N_ * C_;
  int t = threadIdx.x;       // 0..511
  int w = t >> 6;            // wave 0..7
  int l = t & 63;
  int l15 = l & 15, lg = l >> 4;
  int wr = w >> 2, wc = w & 3;   // phase-1 role: rows [32wr,32wr+32), cols j in {wc, wc+4, wc+8}
  int hf = w >> 1, dp = w & 1;   // phase-2 role: h-frag hf, d-frags {2dp, 2dp+1}

  // 32 KB: x tile [64][256] bf16 swizzled; after phase 1, first 24 KB is
  // overlaid with pT (8K) | vT (8K) | qs (8K).
  __shared__ __align__(16) char xsb[32768];
  char* pTb = xsb;
  char* vTb = xsb + 8192;
  char* qsb = xsb + 16384;

  const char* wbase = (const char*)wpack + (size_t)s * 12 * 8 * 64 * 16;

  f32x4 nwacc[2];
#pragma unroll
  for (int j2 = 0; j2 < 2; ++j2) { f32x4 z = {0.f,0.f,0.f,0.f}; nwacc[j2] = z; }
  float zacc = 0.f;

  // prologue: stage tile 0 (serial, once)
  {
    const f32x4* xsrc = (const f32x4*)(x + (size_t)(slot * 64) * C_);
#pragma unroll 1
    for (int g2 = 0; g2 < 2; ++g2) {
#pragma unroll
      for (int i = 0; i < 4; ++i) {
        int f = t + 512 * (g2 * 4 + i);  // chunk id; row = f>>6
        int row = f >> 6;
        f32x4 v = xsrc[f];
        ushort4 pk;
        pk.x = f2bf(v[0]); pk.y = f2bf(v[1]); pk.z = f2bf(v[2]); pk.w = f2bf(v[3]);
        int off = (f * 8) ^ ((row & 7) << 4);
        *(ushort4*)(xsb + off) = pk;
      }
    }
  }
  __syncthreads();

  for (int it = 0; it < 4; ++it) {
    int n0 = (slot + it * 64) * 64;  // token base within (b,s)

    // T14 issue-early: next tile's 8 f32x4 loads start now; latency hides
    // under phase1+repack+phase2. Written to LDS after the phase-2 barrier.
    f32x4 pf[8];
    if (it < 3) {
      const f32x4* xn = (const f32x4*)(x + (size_t)((slot + (it + 1) * 64) * 64) * C_);
#pragma unroll
      for (int i = 0; i < 8; ++i) pf[i] = xn[t + 512 * i];
    }

    // phase 1: [64 tok][256] @ [256][192] -> k|q|v
    // weight B-frags (L2-resident) loaded per-ks; full unroll lets the
    // compiler pipeline them.
    f32x4 acc[2][3];
#pragma unroll
    for (int rf = 0; rf < 2; ++rf)
#pragma unroll
      for (int jj = 0; jj < 3; ++jj) { f32x4 z = {0.f,0.f,0.f,0.f}; acc[rf][jj] = z; }

#pragma unroll
    for (int ks = 0; ks < 8; ++ks) {
      bf16x8 bfr[3];
#pragma unroll
      for (int jj = 0; jj < 3; ++jj)
        bfr[jj] = *(const bf16x8*)(wbase + (((size_t)((wc + 4*jj)*8 + ks))*64 + l)*16);
      bf16x8 a[2];
#pragma unroll
      for (int rf = 0; rf < 2; ++rf) {
        int row = (wr * 2 + rf) * 16 + l15;
        int off = (row * 512 + ks * 64 + lg * 16) ^ ((row & 7) << 4);
        a[rf] = *(const bf16x8*)(xsb + off);
      }
#pragma unroll
      for (int jj = 0; jj < 3; ++jj)
#pragma unroll
        for (int rf = 0; rf < 2; ++rf)
          acc[rf][jj] = __builtin_amdgcn_mfma_f32_16x16x32_bf16(
              a[rf], bfr[jj], acc[rf][jj], 0, 0, 0);
    }
    __syncthreads();   // all xs reads done; overlay region becomes writable

    // fragment processing. token idx within tile: n = (wr*2+rf)*16 + lg*4 + r
    // k (jj=0): exp -> pT[h][n] + z
    {
      int hcol = wc * 16 + l15;
      float zl = 0.f;
#pragma unroll
      for (int rf = 0; rf < 2; ++rf)
#pragma unroll
        for (int r = 0; r < 4; ++r) {
          float ev = __expf(acc[rf][0][r]);
          zl += ev;
          int n = (wr * 2 + rf) * 16 + lg * 4 + r;
          int off = (hcol * 128 + n * 2) ^ ((hcol & 7) << 4);
          *(unsigned short*)(pTb + off) = f2bf(ev);
        }
      zl += __shfl_xor(zl, 16);
      zl += __shfl_xor(zl, 32);
      zacc += zl;
    }
    // q (jj=1): bf16 into qs [n][64 h]
    {
#pragma unroll
      for (int rf = 0; rf < 2; ++rf)
#pragma unroll
        for (int r = 0; r < 4; ++r) {
          int n = (wr * 2 + rf) * 16 + lg * 4 + r;
          int off = (n * 128 + (wc * 16 + l15) * 2) ^ ((n & 7) << 4);
          *(unsigned short*)(qsb + off) = f2bf(acc[rf][1][r]);
        }
    }
    // v (jj=2): vT[d][n]
    {
      int dcol = wc * 16 + l15;
#pragma unroll
      for (int rf = 0; rf < 2; ++rf)
#pragma unroll
        for (int r = 0; r < 4; ++r) {
          int n = (wr * 2 + rf) * 16 + lg * 4 + r;
          int off = (dcol * 128 + n * 2) ^ ((dcol & 7) << 4);
          *(unsigned short*)(vTb + off) = f2bf(acc[rf][2][r]);
        }
    }
    __syncthreads();

    // q readout: coalesced bf16 store to global (512 chunks, 1 per thread)
    {
      unsigned short* qg = qbuf + ((size_t)bs * N_ + n0) * 64;
      int n = t >> 3, c = t & 7;
      int off = (n * 128 + c * 16) ^ ((n & 7) << 4);
      us8 v = *(const us8*)(qsb + off);
      *(us8*)(qg + (size_t)t * 8) = v;
    }

    // phase 2: nw[h][d] += P^T V over this tile's 64 tokens
#pragma unroll
    for (int k2 = 0; k2 < 2; ++k2) {
      int hh = hf * 16 + l15;
      int aoff = (hh * 128 + (k2 * 32 + lg * 8) * 2) ^ ((hh & 7) << 4);
      bf16x8 a2 = *(const bf16x8*)(pTb + aoff);
#pragma unroll
      for (int df = 0; df < 2; ++df) {
        int dd = (dp * 2 + df) * 16 + l15;
        int boff = (dd * 128 + (k2 * 32 + lg * 8) * 2) ^ ((dd & 7) << 4);
        bf16x8 b2 = *(const bf16x8*)(vTb + boff);
        nwacc[df] = __builtin_amdgcn_mfma_f32_16x16x32_bf16(a2, b2, nwacc[df], 0, 0, 0);
      }
    }
    __syncthreads();   // overlays dead; xsb writable

    // T14 write-late: convert prefetched regs, store to LDS for next tile
    if (it < 3) {
#pragma unroll
      for (int i = 0; i < 8; ++i) {
        int f = t + 512 * i;
        int row = f >> 6;
        ushort4 pk;
        pk.x = f2bf(pf[i][0]); pk.y = f2bf(pf[i][1]);
        pk.z = f2bf(pf[i][2]); pk.w = f2bf(pf[i][3]);
        int off = (f * 8) ^ ((row & 7) << 4);
        *(ushort4*)(xsb + off) = pk;
      }
    }
    __syncthreads();   // next phase 1 reads xsb
  }

  // write partials
#pragma unroll
  for (int df = 0; df < 2; ++df)
#pragma unroll
    for (int r = 0; r < 4; ++r) {
      int h = hf * 16 + lg * 4 + r;
      int d = (dp * 2 + df) * 16 + l15;
      pnw[(((size_t)bs * 64 + slot) * 64 + h) * 64 + d] = nwacc[df][r];
    }
  if (lg == 0)
    pz[(((size_t)bs * 64 + slot) * 2 + wr) * 64 + wc * 16 + l15] = zacc;
}

__global__ __launch_bounds__(256) void kB_reduce(
    const float* __restrict__ pnw, const float* __restrict__ pz,
    float* __restrict__ wfin) {
  int g = blockIdx.x;   // 0..15: idx range [g*256, g*256+256) => h in [g*4, g*4+4)
  int bs = blockIdx.y;  // 0..7
  int t = threadIdx.x;
  int wv = t >> 6, l = t & 63;
  __shared__ float zinv[4];
  int h = g * 4 + wv;
  float z = pz[((size_t)bs * 128 + l) * 64 + h] +
            pz[((size_t)bs * 128 + 64 + l) * 64 + h];
#pragma unroll
  for (int m = 32; m; m >>= 1) z += __shfl_xor(z, m);
  if (l == 0) zinv[wv] = 1.f / z;
  __syncthreads();
  int idx = g * 256 + t;
  float ssum = 0.f;
#pragma unroll 8
  for (int p = 0; p < 64; ++p)
    ssum += pnw[((size_t)bs * 64 + p) * 4096 + idx];
  wfin[(size_t)bs * 4096 + idx] = ssum * zinv[wv];
}

__global__ __launch_bounds__(256) void kC_out(
    const unsigned short* __restrict__ qbuf, const float* __restrict__ wfin,
    float* __restrict__ out) {
  int bs = blockIdx.y, b = bs >> 1, s = bs & 1;
  int t = threadIdx.x;
  int w = t >> 6, l = t & 63;
  int l15 = l & 15, lg = l >> 4;
  int tok0 = blockIdx.x * 64;

  __shared__ __align__(16) char cb[16384];
  char* plb = cb;            // P bf16 [64 tok][64 h], swizzled (8K)
  char* wlb = cb + 8192;     // W^T bf16 [64 d][64 h], swizzled (8K)
  float* ob = (float*)cb;    // out f32 [64 tok][64 d] (16K, aliases after MFMA)

  // 1. load w_{1-s}, transpose to [d][h] bf16 swizzled — all 4096 elements
  const float* wsrc = wfin + (size_t)(b * 2 + (1 - s)) * 4096;
#pragma unroll
  for (int rr = 0; rr < 4; ++rr) {
    int fi = t + 256 * rr;        // f32x4 chunk id, [0,1024)
    int h = fi >> 4, d4 = (fi & 15) * 4;
    f32x4 v = *(const f32x4*)(wsrc + h * 64 + d4);
#pragma unroll
    for (int e = 0; e < 4; ++e) {
      int d = d4 + e;
      int off = (d * 128 + h * 2) ^ ((d & 7) << 4);
      *(unsigned short*)(wlb + off) = f2bf(v[e]);
    }
  }

  // 2. q row: exp, quad-reduce sum, normalize, bf16 -> pl
  {
    int tl = t >> 2, p4 = t & 3;
    const unsigned short* qr =
        qbuf + ((size_t)bs * N_ + tok0 + tl) * 64 + p4 * 16;
    us8 u0 = *(const us8*)(qr);
    us8 u1 = *(const us8*)(qr + 8);
    float e[16]; float sum = 0.f;
#pragma unroll
    for (int i = 0; i < 8; ++i) { e[i] = __expf(bf2f(u0[i])); sum += e[i]; }
#pragma unroll
    for (int i = 0; i < 8; ++i) { e[8+i] = __expf(bf2f(u1[i])); sum += e[8+i]; }
    sum += __shfl_xor(sum, 1);
    sum += __shfl_xor(sum, 2);
    float inv = 1.f / sum;
    us8 p0, p1;
#pragma unroll
    for (int i = 0; i < 8; ++i) { p0[i] = f2bf(e[i] * inv); p1[i] = f2bf(e[8+i] * inv); }
    int off = (tl * 128 + p4 * 32) ^ ((tl & 7) << 4);
    *(us8*)(plb + off) = p0;
    *(us8*)(plb + (off ^ 16)) = p1;   // +16 within same 32B chunk (p4*32 has bit4=0)
  }
  __syncthreads();

  // 3. out[64 tok][64 d] = P @ W^T' : 2 K-steps of 16x16x32 MFMA
  f32x4 acc[4];
#pragma unroll
  for (int rf = 0; rf < 4; ++rf) { f32x4 z = {0.f,0.f,0.f,0.f}; acc[rf] = z; }
#pragma unroll
  for (int k2 = 0; k2 < 2; ++k2) {
    int dd = w * 16 + l15;
    int boff = (dd * 128 + (k2 * 32 + lg * 8) * 2) ^ ((dd & 7) << 4);
    bf16x8 bfrag = *(const bf16x8*)(wlb + boff);
#pragma unroll
    for (int rf = 0; rf < 4; ++rf) {
      int row = rf * 16 + l15;
      int aoff = (row * 128 + (k2 * 32 + lg * 8) * 2) ^ ((row & 7) << 4);
      bf16x8 afrag = *(const bf16x8*)(plb + aoff);
      acc[rf] = __builtin_amdgcn_mfma_f32_16x16x32_bf16(afrag, bfrag, acc[rf], 0, 0, 0);
    }
  }
  __syncthreads();   // pl/wl dead; ob takes over

  // 4. fragments -> ob
#pragma unroll
  for (int rf = 0; rf < 4; ++rf)
#pragma unroll
    for (int r = 0; r < 4; ++r) {
      int tok = rf * 16 + lg * 4 + r;
      int d = w * 16 + l15;
      ob[tok * 64 + d] = acc[rf][r];
    }
  __syncthreads();

  // 5. coalesced f32x4 store
  float* outp = out + (size_t)s * ((size_t)B_ * N_ * 64) +
                ((size_t)b * N_ + tok0) * 64;
#pragma unroll
  for (int r2 = 0; r2 < 4; ++r2) {
    int fi = t + 256 * r2;   // 0..1023 f32x4 chunks
    ((f32x4*)outp)[fi] = ((const f32x4*)ob)[fi];
  }
}

extern "C" void kernel_launch(void* const* d_in, const int* in_sizes, int n_in,
                              void* d_out, int out_size, void* d_ws, size_t ws_size,
                              hipStream_t stream) {
  const float* x0  = (const float*)d_in[0];
  const float* x1  = (const float*)d_in[1];
  const float* Wk0 = (const float*)d_in[2];
  const float* Wk1 = (const float*)d_in[3];
  const float* Wq0 = (const float*)d_in[4];
  const float* Wq1 = (const float*)d_in[5];
  const float* Wv0 = (const float*)d_in[6];
  const float* Wv1 = (const float*)d_in[7];
  float* out = (float*)d_out;
  char* wsb = (char*)d_ws;
  unsigned short* wpack = (unsigned short*)(wsb + WPACK_OFF);
  unsigned short* qbuf  = (unsigned short*)(wsb + Q_OFF);
  float* pnw  = (float*)(wsb + PNW_OFF);
  float* pz   = (float*)(wsb + PZ_OFF);
  float* wfin = (float*)(wsb + WFIN_OFF);

  kW_pack<<<dim3(384), dim3(256), 0, stream>>>(Wk0, Wk1, Wq0, Wq1, Wv0, Wv1, wpack);
  kA_proj<<<dim3(64, 8), dim3(512), 0, stream>>>(x0, x1, wpack, qbuf, pnw, pz);
  kB_reduce<<<dim3(16, 8), dim3(256), 0, stream>>>(pnw, pz, wfin);
  kC_out<<<dim3(256, 8), dim3(256), 0, stream>>>(qbuf, wfin, out);
}

// Round 7
// 57.128 us; speedup vs baseline: 4.5730x; 1.0290x over previous
//
#include <hip/hip_runtime.h>

// EfficientCrossAttentionHead: B=4, N=16384, C=256, H=64, fp32 in/out.
//   kW_pack : weights -> bf16 MFMA B-fragment layout in ws
//   kA_proj : 8-wave blocks; persistent weight frags in VGPRs; raw barriers
//             (lgkmcnt-only) so prefetch loads stay in flight; T14 async stage.
//   kB_reduce: partials -> w[bs][64][64] = (sum e*v)/Z
//   kC_out  : out = softmax_row(q_s) @ w_{1-s}  (MFMA, bf16 in / f32 acc)
// ws usage ~25.8 MB.

#define B_ 4
#define N_ 16384
#define C_ 256

typedef float f32x4 __attribute__((ext_vector_type(4)));
typedef __bf16 bf16x8 __attribute__((ext_vector_type(8)));
typedef unsigned short us8 __attribute__((ext_vector_type(8)));

__device__ __forceinline__ unsigned short f2bf(float f) {
  union { float f; unsigned u; } v; v.f = f;
  return (unsigned short)((v.u + 0x7FFFu + ((v.u >> 16) & 1u)) >> 16);
}
__device__ __forceinline__ float bf2f(unsigned short h) {
  union { unsigned u; float f; } v; v.u = ((unsigned)h) << 16;
  return v.f;
}

// LDS-only sync: waits local ops, does NOT drain vmcnt -> global loads/stores
// stay in flight across the barrier (unlike __syncthreads()).
__device__ __forceinline__ void sync_lds() {
  asm volatile("s_waitcnt lgkmcnt(0)" ::: "memory");
  __builtin_amdgcn_sched_barrier(0);
  __builtin_amdgcn_s_barrier();
  __builtin_amdgcn_sched_barrier(0);
}

// ws byte offsets
#define WPACK_OFF 0u           // [2][12][8][64][8] bf16 = 196608 B
#define Q_OFF     262144u      // q logits bf16 [8][16384][64] = 16 MB
#define PNW_OFF   17039360u    // partial nw [8][64][4096] f32 = 8 MB
#define PZ_OFF    25427968u    // partial z  [8][128][64]  f32 = 256 KB
#define WFIN_OFF  25690112u    // w final [8][4096] f32 = 128 KB

__global__ __launch_bounds__(256) void kW_pack(
    const float* __restrict__ Wk0, const float* __restrict__ Wk1,
    const float* __restrict__ Wq0, const float* __restrict__ Wq1,
    const float* __restrict__ Wv0, const float* __restrict__ Wv1,
    unsigned short* __restrict__ wpack) {
  int t = blockIdx.x * 256 + threadIdx.x;  // [0, 98304)
  int i = t & 7;
  int lane = (t >> 3) & 63;
  int q = t >> 9;            // [0,192)
  int ks = q & 7;
  int sj = q >> 3;           // [0,24)
  int s = sj / 12;
  int j = sj - s * 12;       // col-frag 0..11 (k:0-3, q:4-7, v:8-11)
  int gc = 16 * j + (lane & 15);
  int c = 32 * ks + ((lane >> 4) << 3) + i;
  int m = gc >> 6, row = gc & 63;
  const float* W;
  if (s == 0) W = (m == 0) ? Wk0 : (m == 1) ? Wq0 : Wv0;
  else        W = (m == 0) ? Wk1 : (m == 1) ? Wq1 : Wv1;
  wpack[t] = f2bf(W[row * 256 + c]);
}

__global__ __launch_bounds__(512, 2) void kA_proj(
    const float* __restrict__ x0, const float* __restrict__ x1,
    const unsigned short* __restrict__ wpack,
    unsigned short* __restrict__ qbuf, float* __restrict__ pnw,
    float* __restrict__ pz) {
  int slot = blockIdx.x;     // 0..63 partial slot
  int bs = blockIdx.y;       // 0..7 : b = bs>>1, s = bs&1
  int b = bs >> 1, s = bs & 1;
  const float* x = (s ? x1 : x0) + (size_t)b * N_ * C_;
  int t = threadIdx.x;       // 0..511
  int w = t >> 6;            // wave 0..7
  int l = t & 63;
  int l15 = l & 15, lg = l >> 4;
  int wr = w >> 2, wc = w & 3;   // phase-1 role: rows [32wr,32wr+32), cols j in {wc, wc+4, wc+8}
  int hf = w >> 1, dp = w & 1;   // phase-2 role: h-frag hf, d-frags {2dp, 2dp+1}

  // 32 KB: x tile [64][256] bf16 swizzled; after phase 1, first 24 KB is
  // overlaid with pT (8K) | vT (8K) | qs (8K).
  __shared__ __align__(16) char xsb[32768];
  char* pTb = xsb;
  char* vTb = xsb + 8192;
  char* qsb = xsb + 16384;

  const char* wbase = (const char*)wpack + (size_t)s * 12 * 8 * 64 * 16;

  // persistent weight B-fragments: iteration-invariant, 96 VGPRs.
  bf16x8 bfr[3][8];
#pragma unroll
  for (int jj = 0; jj < 3; ++jj)
#pragma unroll
    for (int ks = 0; ks < 8; ++ks)
      bfr[jj][ks] = *(const bf16x8*)(wbase + (((size_t)((wc + 4*jj)*8 + ks))*64 + l)*16);

  f32x4 nwacc[2];
#pragma unroll
  for (int j2 = 0; j2 < 2; ++j2) { f32x4 z = {0.f,0.f,0.f,0.f}; nwacc[j2] = z; }
  float zacc = 0.f;

  // prologue: stage tile 0 (serial, once)
  {
    const f32x4* xsrc = (const f32x4*)(x + (size_t)(slot * 64) * C_);
#pragma unroll 1
    for (int g2 = 0; g2 < 2; ++g2) {
#pragma unroll
      for (int i = 0; i < 4; ++i) {
        int f = t + 512 * (g2 * 4 + i);  // chunk id; row = f>>6
        int row = f >> 6;
        f32x4 v = xsrc[f];
        ushort4 pk;
        pk.x = f2bf(v[0]); pk.y = f2bf(v[1]); pk.z = f2bf(v[2]); pk.w = f2bf(v[3]);
        int off = (f * 8) ^ ((row & 7) << 4);
        *(ushort4*)(xsb + off) = pk;
      }
    }
  }
  sync_lds();

  for (int it = 0; it < 4; ++it) {
    int n0 = (slot + it * 64) * 64;  // token base within (b,s)

    // T14 issue-early: next tile's 8 f32x4 loads. With raw barriers these
    // stay outstanding until the write-late phase (compiler waits on use).
    f32x4 pf[8];
    if (it < 3) {
      const f32x4* xn = (const f32x4*)(x + (size_t)((slot + (it + 1) * 64) * 64) * C_);
#pragma unroll
      for (int i = 0; i < 8; ++i) pf[i] = xn[t + 512 * i];
    }

    // phase 1: [64 tok][256] @ [256][192] -> k|q|v, weights in registers
    f32x4 acc[2][3];
#pragma unroll
    for (int rf = 0; rf < 2; ++rf)
#pragma unroll
      for (int jj = 0; jj < 3; ++jj) { f32x4 z = {0.f,0.f,0.f,0.f}; acc[rf][jj] = z; }

#pragma unroll
    for (int ks = 0; ks < 8; ++ks) {
      bf16x8 a[2];
#pragma unroll
      for (int rf = 0; rf < 2; ++rf) {
        int row = (wr * 2 + rf) * 16 + l15;
        int off = (row * 512 + ks * 64 + lg * 16) ^ ((row & 7) << 4);
        a[rf] = *(const bf16x8*)(xsb + off);
      }
#pragma unroll
      for (int jj = 0; jj < 3; ++jj)
#pragma unroll
        for (int rf = 0; rf < 2; ++rf)
          acc[rf][jj] = __builtin_amdgcn_mfma_f32_16x16x32_bf16(
              a[rf], bfr[jj][ks], acc[rf][jj], 0, 0, 0);
    }
    sync_lds();   // all xs reads done; overlay region becomes writable

    // fragment processing. token idx within tile: n = (wr*2+rf)*16 + lg*4 + r
    // k (jj=0): exp -> pT[h][n] + z   (r=0..3 are col-consecutive: ushort4)
    {
      int hcol = wc * 16 + l15;
      float zl = 0.f;
#pragma unroll
      for (int rf = 0; rf < 2; ++rf) {
        ushort4 pk;
        float e0 = __expf(acc[rf][0][0]), e1 = __expf(acc[rf][0][1]);
        float e2 = __expf(acc[rf][0][2]), e3 = __expf(acc[rf][0][3]);
        zl += e0 + e1 + e2 + e3;
        pk.x = f2bf(e0); pk.y = f2bf(e1); pk.z = f2bf(e2); pk.w = f2bf(e3);
        int nb = (wr * 2 + rf) * 16 + lg * 4;
        int off = (hcol * 128 + nb * 2) ^ ((hcol & 7) << 4);
        *(ushort4*)(pTb + off) = pk;
      }
      zl += __shfl_xor(zl, 16);
      zl += __shfl_xor(zl, 32);
      zacc += zl;
    }
    // q (jj=1): bf16 into qs [n][64 h] (scattered rows, scalar stores)
    {
#pragma unroll
      for (int rf = 0; rf < 2; ++rf)
#pragma unroll
        for (int r = 0; r < 4; ++r) {
          int n = (wr * 2 + rf) * 16 + lg * 4 + r;
          int off = (n * 128 + (wc * 16 + l15) * 2) ^ ((n & 7) << 4);
          *(unsigned short*)(qsb + off) = f2bf(acc[rf][1][r]);
        }
    }
    // v (jj=2): vT[d][n], ushort4 batched
    {
      int dcol = wc * 16 + l15;
#pragma unroll
      for (int rf = 0; rf < 2; ++rf) {
        ushort4 pk;
        pk.x = f2bf(acc[rf][2][0]); pk.y = f2bf(acc[rf][2][1]);
        pk.z = f2bf(acc[rf][2][2]); pk.w = f2bf(acc[rf][2][3]);
        int nb = (wr * 2 + rf) * 16 + lg * 4;
        int off = (dcol * 128 + nb * 2) ^ ((dcol & 7) << 4);
        *(ushort4*)(vTb + off) = pk;
      }
    }
    sync_lds();

    // q readout: coalesced bf16 store to global (512 chunks, 1 per thread)
    {
      unsigned short* qg = qbuf + ((size_t)bs * N_ + n0) * 64;
      int n = t >> 3, c = t & 7;
      int off = (n * 128 + c * 16) ^ ((n & 7) << 4);
      us8 v = *(const us8*)(qsb + off);
      *(us8*)(qg + (size_t)t * 8) = v;
    }

    // phase 2: nw[h][d] += P^T V over this tile's 64 tokens
#pragma unroll
    for (int k2 = 0; k2 < 2; ++k2) {
      int hh = hf * 16 + l15;
      int aoff = (hh * 128 + (k2 * 32 + lg * 8) * 2) ^ ((hh & 7) << 4);
      bf16x8 a2 = *(const bf16x8*)(pTb + aoff);
#pragma unroll
      for (int df = 0; df < 2; ++df) {
        int dd = (dp * 2 + df) * 16 + l15;
        int boff = (dd * 128 + (k2 * 32 + lg * 8) * 2) ^ ((dd & 7) << 4);
        bf16x8 b2 = *(const bf16x8*)(vTb + boff);
        nwacc[df] = __builtin_amdgcn_mfma_f32_16x16x32_bf16(a2, b2, nwacc[df], 0, 0, 0);
      }
    }

    if (it < 3) {
      sync_lds();   // overlays dead; xsb writable
      // T14 write-late: compiler inserts the vmcnt wait on pf here
#pragma unroll
      for (int i = 0; i < 8; ++i) {
        int f = t + 512 * i;
        int row = f >> 6;
        ushort4 pk;
        pk.x = f2bf(pf[i][0]); pk.y = f2bf(pf[i][1]);
        pk.z = f2bf(pf[i][2]); pk.w = f2bf(pf[i][3]);
        int off = (f * 8) ^ ((row & 7) << 4);
        *(ushort4*)(xsb + off) = pk;
      }
      sync_lds();   // next phase 1 reads xsb
    }
  }

  // write partials
#pragma unroll
  for (int df = 0; df < 2; ++df)
#pragma unroll
    for (int r = 0; r < 4; ++r) {
      int h = hf * 16 + lg * 4 + r;
      int d = (dp * 2 + df) * 16 + l15;
      pnw[(((size_t)bs * 64 + slot) * 64 + h) * 64 + d] = nwacc[df][r];
    }
  if (lg == 0)
    pz[(((size_t)bs * 64 + slot) * 2 + wr) * 64 + wc * 16 + l15] = zacc;
}

__global__ __launch_bounds__(256) void kB_reduce(
    const float* __restrict__ pnw, const float* __restrict__ pz,
    float* __restrict__ wfin) {
  int g = blockIdx.x;   // 0..15: idx range [g*256, g*256+256) => h in [g*4, g*4+4)
  int bs = blockIdx.y;  // 0..7
  int t = threadIdx.x;
  int wv = t >> 6, l = t & 63;
  __shared__ float zinv[4];
  int h = g * 4 + wv;
  float z = pz[((size_t)bs * 128 + l) * 64 + h] +
            pz[((size_t)bs * 128 + 64 + l) * 64 + h];
#pragma unroll
  for (int m = 32; m; m >>= 1) z += __shfl_xor(z, m);
  if (l == 0) zinv[wv] = 1.f / z;
  __syncthreads();
  int idx = g * 256 + t;
  float ssum = 0.f;
#pragma unroll 8
  for (int p = 0; p < 64; ++p)
    ssum += pnw[((size_t)bs * 64 + p) * 4096 + idx];
  wfin[(size_t)bs * 4096 + idx] = ssum * zinv[wv];
}

__global__ __launch_bounds__(256) void kC_out(
    const unsigned short* __restrict__ qbuf, const float* __restrict__ wfin,
    float* __restrict__ out) {
  int bs = blockIdx.y, b = bs >> 1, s = bs & 1;
  int t = threadIdx.x;
  int w = t >> 6, l = t & 63;
  int l15 = l & 15, lg = l >> 4;
  int tok0 = blockIdx.x * 64;

  __shared__ __align__(16) char cb[16384];
  char* plb = cb;            // P bf16 [64 tok][64 h], swizzled (8K)
  char* wlb = cb + 8192;     // W^T bf16 [64 d][64 h], swizzled (8K)
  float* ob = (float*)cb;    // out f32 [64 tok][64 d] (16K, aliases after MFMA)

  // 1. load w_{1-s}, transpose to [d][h] bf16 swizzled — all 4096 elements
  const float* wsrc = wfin + (size_t)(b * 2 + (1 - s)) * 4096;
#pragma unroll
  for (int rr = 0; rr < 4; ++rr) {
    int fi = t + 256 * rr;        // f32x4 chunk id, [0,1024)
    int h = fi >> 4, d4 = (fi & 15) * 4;
    f32x4 v = *(const f32x4*)(wsrc + h * 64 + d4);
#pragma unroll
    for (int e = 0; e < 4; ++e) {
      int d = d4 + e;
      int off = (d * 128 + h * 2) ^ ((d & 7) << 4);
      *(unsigned short*)(wlb + off) = f2bf(v[e]);
    }
  }

  // 2. q row: exp, quad-reduce sum, normalize, bf16 -> pl
  {
    int tl = t >> 2, p4 = t & 3;
    const unsigned short* qr =
        qbuf + ((size_t)bs * N_ + tok0 + tl) * 64 + p4 * 16;
    us8 u0 = *(const us8*)(qr);
    us8 u1 = *(const us8*)(qr + 8);
    float e[16]; float sum = 0.f;
#pragma unroll
    for (int i = 0; i < 8; ++i) { e[i] = __expf(bf2f(u0[i])); sum += e[i]; }
#pragma unroll
    for (int i = 0; i < 8; ++i) { e[8+i] = __expf(bf2f(u1[i])); sum += e[8+i]; }
    sum += __shfl_xor(sum, 1);
    sum += __shfl_xor(sum, 2);
    float inv = 1.f / sum;
    us8 p0, p1;
#pragma unroll
    for (int i = 0; i < 8; ++i) { p0[i] = f2bf(e[i] * inv); p1[i] = f2bf(e[8+i] * inv); }
    int off = (tl * 128 + p4 * 32) ^ ((tl & 7) << 4);
    *(us8*)(plb + off) = p0;
    *(us8*)(plb + (off ^ 16)) = p1;   // +16 within same 32B chunk (p4*32 has bit4=0)
  }
  __syncthreads();

  // 3. out[64 tok][64 d] = P @ W^T' : 2 K-steps of 16x16x32 MFMA
  f32x4 acc[4];
#pragma unroll
  for (int rf = 0; rf < 4; ++rf) { f32x4 z = {0.f,0.f,0.f,0.f}; acc[rf] = z; }
#pragma unroll
  for (int k2 = 0; k2 < 2; ++k2) {
    int dd = w * 16 + l15;
    int boff = (dd * 128 + (k2 * 32 + lg * 8) * 2) ^ ((dd & 7) << 4);
    bf16x8 bfrag = *(const bf16x8*)(wlb + boff);
#pragma unroll
    for (int rf = 0; rf < 4; ++rf) {
      int row = rf * 16 + l15;
      int aoff = (row * 128 + (k2 * 32 + lg * 8) * 2) ^ ((row & 7) << 4);
      bf16x8 afrag = *(const bf16x8*)(plb + aoff);
      acc[rf] = __builtin_amdgcn_mfma_f32_16x16x32_bf16(afrag, bfrag, acc[rf], 0, 0, 0);
    }
  }
  __syncthreads();   // pl/wl dead; ob takes over

  // 4. fragments -> ob
#pragma unroll
  for (int rf = 0; rf < 4; ++rf)
#pragma unroll
    for (int r = 0; r < 4; ++r) {
      int tok = rf * 16 + lg * 4 + r;
      int d = w * 16 + l15;
      ob[tok * 64 + d] = acc[rf][r];
    }
  __syncthreads();

  // 5. coalesced f32x4 store
  float* outp = out + (size_t)s * ((size_t)B_ * N_ * 64) +
                ((size_t)b * N_ + tok0) * 64;
#pragma unroll
  for (int r2 = 0; r2 < 4; ++r2) {
    int fi = t + 256 * r2;   // 0..1023 f32x4 chunks
    ((f32x4*)outp)[fi] = ((const f32x4*)ob)[fi];
  }
}

extern "C" void kernel_launch(void* const* d_in, const int* in_sizes, int n_in,
                              void* d_out, int out_size, void* d_ws, size_t ws_size,
                              hipStream_t stream) {
  const float* x0  = (const float*)d_in[0];
  const float* x1  = (const float*)d_in[1];
  const float* Wk0 = (const float*)d_in[2];
  const float* Wk1 = (const float*)d_in[3];
  const float* Wq0 = (const float*)d_in[4];
  const float* Wq1 = (const float*)d_in[5];
  const float* Wv0 = (const float*)d_in[6];
  const float* Wv1 = (const float*)d_in[7];
  float* out = (float*)d_out;
  char* wsb = (char*)d_ws;
  unsigned short* wpack = (unsigned short*)(wsb + WPACK_OFF);
  unsigned short* qbuf  = (unsigned short*)(wsb + Q_OFF);
  float* pnw  = (float*)(wsb + PNW_OFF);
  float* pz   = (float*)(wsb + PZ_OFF);
  float* wfin = (float*)(wsb + WFIN_OFF);

  kW_pack<<<dim3(384), dim3(256), 0, stream>>>(Wk0, Wk1, Wq0, Wq1, Wv0, Wv1, wpack);
  kA_proj<<<dim3(64, 8), dim3(512), 0, stream>>>(x0, x1, wpack, qbuf, pnw, pz);
  kB_reduce<<<dim3(16, 8), dim3(256), 0, stream>>>(pnw, pz, wfin);
  kC_out<<<dim3(256, 8), dim3(256), 0, stream>>>(qbuf, wfin, out);
}